// Round 2
// baseline (1080.205 us; speedup 1.0000x reference)
//
#include <hip/hip_runtime.h>

#define BB 8
#define TT 4
#define CIN 512
#define CAF 64
#define HH 11
#define WW 20
#define AREAL 2784
#define AP 2816          // padded anchors
#define DD 704           // C_AF*H
#define DP 768           // padded D
#define NH 80            // padded head cols (2 cls + 74 reg)
#define KH 3520          // 5*DD
#define NATT 2783        // A-1

typedef __attribute__((ext_vector_type(8))) short bf16x8;
typedef __attribute__((ext_vector_type(4))) float floatx4;

__device__ __forceinline__ short f2bf(float f) {
  unsigned u = __float_as_uint(f);
  u += 0x7fffu + ((u >> 16) & 1u);
  return (short)(u >> 16);
}
__device__ __forceinline__ float bf2f(short s) {
  return __uint_as_float(((unsigned)(unsigned short)s) << 16);
}

// ---------------- conv1x1 (batched over all 32 bt): feats[bt][o][h][w]
__global__ __launch_bounds__(256)
void conv_kernel(const float* __restrict__ x, const float* __restrict__ w,
                 const float* __restrict__ bias, float* __restrict__ feats)
{
  int bt = blockIdx.x;   // 0..31
  int h  = blockIdx.y;   // 0..10
  __shared__ float xs[CIN * WW];   // 40KB
  int tid = threadIdx.x;
  const float* xp = x + (long)bt * CIN * HH * WW + h * WW;
  for (int i = tid; i < CIN * WW; i += 256) {
    int c = i / WW, ww = i % WW;
    xs[i] = xp[(long)c * HH * WW + ww];
  }
  __syncthreads();
  for (int i = tid; i < CAF * WW; i += 256) {
    int o = i / WW, ww = i % WW;
    float acc = bias[o];
    const float* wp = w + (long)o * CIN;
    #pragma unroll 8
    for (int c = 0; c < CIN; ++c) acc += xs[c * WW + ww] * wp[c];
    feats[((long)bt * CAF + o) * HH * WW + h * WW + ww] = acc;
  }
}

// ---------------- per-b gather: rois_b[t][a][o*11+h] (bf16), pad rows zero
__global__ __launch_bounds__(256)
void gather_kernel(const float* __restrict__ feats_b, const int* __restrict__ cut_xs,
                   const int* __restrict__ invalid, short* __restrict__ rois_b)
{
  int t  = blockIdx.y;                         // 0..3
  int a  = blockIdx.x * 4 + (threadIdx.x >> 6);
  int o  = threadIdx.x & 63;
  short* outp = rois_b + ((long)t * AP + a) * DD + o * HH;
  if (a >= AREAL) {
    #pragma unroll
    for (int hh = 0; hh < HH; ++hh) outp[hh] = 0;
    return;
  }
  const float* fp = feats_b + ((long)t * CAF + o) * HH * WW;
  #pragma unroll
  for (int hh = 0; hh < HH; ++hh) {
    int xw = cut_xs[a * HH + hh];
    float v = invalid[a * HH + hh] ? 0.f : fp[hh * WW + xw];
    outp[hh] = f2bf(v);
  }
}

// ---------------- curT_b[d][j] = cur_b[j][d]  (d<704 real, else 0)
__global__ __launch_bounds__(256)
void transpose_cur_kernel(const short* __restrict__ rois_b, short* __restrict__ curT_b)
{
  int j0 = blockIdx.x * 32;
  int d0 = blockIdx.y * 32;
  __shared__ short tile[32][33];
  const short* cur = rois_b + (long)3 * AP * DD;
  int tid = threadIdx.x;
  for (int i = tid; i < 1024; i += 256) {
    int r = i >> 5, c = i & 31;     // r: j-off, c: d-off
    int d = d0 + c;
    tile[r][c] = (d < DD) ? cur[(long)(j0 + r) * DD + d] : (short)0;
  }
  __syncthreads();
  for (int i = tid; i < 1024; i += 256) {
    int r = i >> 5, c = i & 31;     // r: d-off, c: j-off
    curT_b[((long)(d0 + r)) * AP + j0 + c] = tile[c][r];
  }
}

// ---------------- attw_T[n][d] = att_w[d][n] bf16 (pad -> 0)
__global__ __launch_bounds__(256)
void prep_attw_kernel(const float* __restrict__ att_w, short* __restrict__ attwT)
{
  int n0 = blockIdx.x * 32;
  int d0 = blockIdx.y * 32;
  __shared__ float tile[32][33];
  int tid = threadIdx.x;
  for (int i = tid; i < 1024; i += 256) {
    int r = i >> 5, c = i & 31;     // r: d, c: n
    int d = d0 + r, n = n0 + c;
    tile[r][c] = (d < DD && n < NATT) ? att_w[(long)d * NATT + n] : 0.f;
  }
  __syncthreads();
  for (int i = tid; i < 1024; i += 256) {
    int r = i >> 5, c = i & 31;     // r: n, c: d
    attwT[(long)(n0 + r) * DD + d0 + c] = f2bf(tile[c][r]);
  }
}

// ---------------- headwT[n][k]: n<2 cls_w[k][n]; 2<=n<76 reg_w[k][n-2]; else 0
__global__ void prep_headw_kernel(const float* __restrict__ cls_w, const float* __restrict__ reg_w,
                                  short* __restrict__ headwT)
{
  long idx = (long)blockIdx.x * 256 + threadIdx.x;
  if (idx >= (long)NH * KH) return;
  int n = (int)(idx / KH), k = (int)(idx % KH);
  float v = 0.f;
  if (n < 2) v = cls_w[(long)k * 2 + n];
  else if (n < 76) v = reg_w[(long)k * 74 + (n - 2)];
  headwT[idx] = f2bf(v);
}

// ---------------- NT GEMM: C[m][n] = sum_k A[m][k]*Bt[n][k]  (bf16 in/out, fp32 acc)
// 128x128 tile, BK=32, 4 waves (2x2), 16x16x32 bf16 MFMA.
template<int WITH_BIAS>
__global__ __launch_bounds__(256)
void gemm_nt_kernel(const short* __restrict__ A, int lda,
                    const short* __restrict__ Bt, int ldb,
                    short* __restrict__ C, int ldc,
                    int K, const float* __restrict__ bias, int biasN)
{
  int m0 = blockIdx.y * 128;
  int n0 = blockIdx.x * 128;

  __shared__ short lds_a[128 * 32];
  __shared__ short lds_b[128 * 32];

  int tid = threadIdx.x;
  int lane = tid & 63;
  int wid = tid >> 6;
  int wr = wid >> 1, wc = wid & 1;
  int srow = tid >> 2;    // 0..63
  int sp   = tid & 3;     // physical kslot

  floatx4 acc[4][4];
  #pragma unroll
  for (int m = 0; m < 4; ++m)
    #pragma unroll
    for (int n = 0; n < 4; ++n) acc[m][n] = floatx4{0.f, 0.f, 0.f, 0.f};

  bf16x8 ra[2], rb[2], na[2], nb[2];

  auto stage_load = [&](int kt, bf16x8* r_a, bf16x8* r_b) {
    int k0 = kt * 32;
    #pragma unroll
    for (int it = 0; it < 2; ++it) {
      int row = it * 64 + srow;
      int ks = sp ^ ((row >> 1) & 3);
      r_a[it] = *(const bf16x8*)(A  + (long)(m0 + row) * lda + k0 + ks * 8);
      r_b[it] = *(const bf16x8*)(Bt + (long)(n0 + row) * ldb + k0 + ks * 8);
    }
  };
  auto stage_write = [&](bf16x8* r_a, bf16x8* r_b) {
    #pragma unroll
    for (int it = 0; it < 2; ++it) {
      int row = it * 64 + srow;
      *(bf16x8*)((char*)lds_a + row * 64 + (sp << 4)) = r_a[it];
      *(bf16x8*)((char*)lds_b + row * 64 + (sp << 4)) = r_b[it];
    }
  };
  auto read_a = [&](int fm) -> bf16x8 {
    int row = wr * 64 + fm * 16 + (lane & 15);
    int pp = (lane >> 4) ^ ((row >> 1) & 3);
    return *(const bf16x8*)((const char*)lds_a + row * 64 + (pp << 4));
  };
  auto read_b = [&](int fn) -> bf16x8 {
    int row = wc * 64 + fn * 16 + (lane & 15);
    int pp = (lane >> 4) ^ ((row >> 1) & 3);
    return *(const bf16x8*)((const char*)lds_b + row * 64 + (pp << 4));
  };

  int nk = K >> 5;
  stage_load(0, ra, rb);
  stage_write(ra, rb);
  __syncthreads();
  for (int kt = 0; kt < nk; ++kt) {
    bool more = (kt + 1 < nk);
    if (more) stage_load(kt + 1, na, nb);
    bf16x8 af[4], bfv[4];
    #pragma unroll
    for (int m = 0; m < 4; ++m) af[m] = read_a(m);
    #pragma unroll
    for (int n = 0; n < 4; ++n) bfv[n] = read_b(n);
    #pragma unroll
    for (int m = 0; m < 4; ++m)
      #pragma unroll
      for (int n = 0; n < 4; ++n)
        acc[m][n] = __builtin_amdgcn_mfma_f32_16x16x32_bf16(af[m], bfv[n], acc[m][n], 0, 0, 0);
    __syncthreads();
    if (more) stage_write(na, nb);
    __syncthreads();
  }

  #pragma unroll
  for (int m = 0; m < 4; ++m) {
    #pragma unroll
    for (int n = 0; n < 4; ++n) {
      int col = n0 + wc * 64 + n * 16 + (lane & 15);
      float bv = 0.f;
      if (WITH_BIAS) bv = (col < biasN) ? bias[col] : 0.f;
      #pragma unroll
      for (int r = 0; r < 4; ++r) {
        int row = m0 + wr * 64 + m * 16 + (lane >> 4) * 4 + r;
        C[(long)row * ldc + col] = f2bf(acc[m][n][r] + bv);
      }
    }
  }
}

// ---------------- per-row softmax over 2783 scores, then write shifted M-row in place:
// Mfull[i][j] = att[i][j-(j>i)], diag 0, j>=2784 -> 0
__global__ __launch_bounds__(256)
void softmax_shift_kernel(short* __restrict__ scores_b)
{
  int i = blockIdx.x;   // 0..2783
  short* row = scores_b + (long)i * AP;
  __shared__ float vals[NATT];
  __shared__ float red[4];
  int tid = threadIdx.x;

  float lmax = -1e30f;
  for (int j = tid; j < NATT; j += 256) {
    float v = bf2f(row[j]);
    vals[j] = v;
    lmax = fmaxf(lmax, v);
  }
  #pragma unroll
  for (int off = 32; off; off >>= 1) lmax = fmaxf(lmax, __shfl_down(lmax, off, 64));
  if ((tid & 63) == 0) red[tid >> 6] = lmax;
  __syncthreads();
  float mx = fmaxf(fmaxf(red[0], red[1]), fmaxf(red[2], red[3]));
  __syncthreads();

  float lsum = 0.f;
  for (int j = tid; j < NATT; j += 256) {
    float e = __expf(vals[j] - mx);
    vals[j] = e;
    lsum += e;
  }
  #pragma unroll
  for (int off = 32; off; off >>= 1) lsum += __shfl_down(lsum, off, 64);
  if ((tid & 63) == 0) red[tid >> 6] = lsum;
  __syncthreads();
  float inv = 1.f / (red[0] + red[1] + red[2] + red[3]);
  __syncthreads();

  for (int j = tid; j < AP; j += 256) {
    float v;
    if (j < i)            v = vals[j] * inv;
    else if (j == i)      v = 0.f;
    else if (j < AREAL)   v = vals[j - 1] * inv;
    else                  v = 0.f;
    row[j] = f2bf(v);
  }
}

// ---------------- heads GEMM, split-K over the 5 chunks of 704:
// linpart[kc][a][n] = sum_{k in chunk kc} headin[a][k]*headwT[n][kc*704+k]
__global__ __launch_bounds__(256)
void gemm_heads_split(const short* __restrict__ rois_b, const short* __restrict__ attft_b,
                      const short* __restrict__ headwT, float* __restrict__ linpart)
{
  int kc = blockIdx.x;        // 0..4
  int m0 = blockIdx.y * 128;
  const short* abase; int ald;
  if (kc == 3) { abase = attft_b; ald = DP; }
  else { int t = (kc == 4) ? 3 : kc; abase = rois_b + (long)t * AP * DD; ald = DD; }
  const short* hb = headwT + kc * DD;

  __shared__ short lds_a[128 * 32];
  __shared__ short lds_b[NH * 32];
  int tid = threadIdx.x, lane = tid & 63, wid = tid >> 6;

  floatx4 acc[2][5];
  #pragma unroll
  for (int m = 0; m < 2; ++m)
    #pragma unroll
    for (int n = 0; n < 5; ++n) acc[m][n] = floatx4{0.f, 0.f, 0.f, 0.f};

  bf16x8 ra[2], rb0, rb1, xa[2], xb0, xb1;
  bool has2 = (tid < 64);

  auto stage_load = [&](int kt, bf16x8* r_a, bf16x8& r_b0, bf16x8& r_b1) {
    int kk = kt * 32;
    #pragma unroll
    for (int it = 0; it < 2; ++it) {
      int row = it * 64 + (tid >> 2);
      int ks = (tid & 3) ^ ((row >> 1) & 3);
      r_a[it] = *(const bf16x8*)(abase + (long)(m0 + row) * ald + kk + ks * 8);
    }
    {
      int n = tid >> 2;
      int ks = (tid & 3) ^ ((n >> 1) & 3);
      r_b0 = *(const bf16x8*)(hb + (long)n * KH + kk + ks * 8);
    }
    if (has2) {
      int n = (tid + 256) >> 2;
      int ks = (tid & 3) ^ ((n >> 1) & 3);
      r_b1 = *(const bf16x8*)(hb + (long)n * KH + kk + ks * 8);
    }
  };
  auto stage_write = [&](bf16x8* r_a, bf16x8& r_b0, bf16x8& r_b1) {
    #pragma unroll
    for (int it = 0; it < 2; ++it) {
      int row = it * 64 + (tid >> 2);
      *(bf16x8*)((char*)lds_a + row * 64 + ((tid & 3) << 4)) = r_a[it];
    }
    { int n = tid >> 2;
      *(bf16x8*)((char*)lds_b + n * 64 + ((tid & 3) << 4)) = r_b0; }
    if (has2) {
      int n = (tid + 256) >> 2;
      *(bf16x8*)((char*)lds_b + n * 64 + ((tid & 3) << 4)) = r_b1;
    }
  };
  auto read_a = [&](int fm) -> bf16x8 {
    int row = wid * 32 + fm * 16 + (lane & 15);
    int pp = (lane >> 4) ^ ((row >> 1) & 3);
    return *(const bf16x8*)((const char*)lds_a + row * 64 + (pp << 4));
  };
  auto read_b = [&](int fn) -> bf16x8 {
    int n = fn * 16 + (lane & 15);
    int pp = (lane >> 4) ^ ((n >> 1) & 3);
    return *(const bf16x8*)((const char*)lds_b + n * 64 + (pp << 4));
  };

  const int nk = 22;  // 704/32
  stage_load(0, ra, rb0, rb1);
  stage_write(ra, rb0, rb1);
  __syncthreads();
  for (int kt = 0; kt < nk; ++kt) {
    bool more = (kt + 1 < nk);
    if (more) stage_load(kt + 1, xa, xb0, xb1);
    bf16x8 af[2], bfv[5];
    #pragma unroll
    for (int m = 0; m < 2; ++m) af[m] = read_a(m);
    #pragma unroll
    for (int n = 0; n < 5; ++n) bfv[n] = read_b(n);
    #pragma unroll
    for (int m = 0; m < 2; ++m)
      #pragma unroll
      for (int n = 0; n < 5; ++n)
        acc[m][n] = __builtin_amdgcn_mfma_f32_16x16x32_bf16(af[m], bfv[n], acc[m][n], 0, 0, 0);
    __syncthreads();
    if (more) stage_write(xa, xb0, xb1);
    __syncthreads();
  }

  float* lp = linpart + (long)kc * AP * NH;
  #pragma unroll
  for (int fm = 0; fm < 2; ++fm)
    #pragma unroll
    for (int fn = 0; fn < 5; ++fn)
      #pragma unroll
      for (int r = 0; r < 4; ++r) {
        int row = m0 + wid * 32 + fm * 16 + (lane >> 4) * 4 + r;
        int col = fn * 16 + (lane & 15);
        lp[(long)row * NH + col] = acc[fm][fn][r];
      }
}

// ---------------- assemble output for one b: out_b[a][c], summing 5 K-partials
__global__ void assemble_kernel(const float* __restrict__ linpart, const float* __restrict__ anchors,
                                const float* __restrict__ cls_b, const float* __restrict__ reg_b,
                                float* __restrict__ out_b)
{
  long idx = (long)blockIdx.x * 256 + threadIdx.x;
  const long total = (long)AREAL * 77;
  if (idx >= total) return;
  int c = (int)(idx % 77);
  int a = (int)(idx / 77);
  float v;
  if (c == 2) {
    v = anchors[(long)a * 77 + 2];
  } else {
    int col = (c < 2) ? c : (2 + (c - 3));
    float s = 0.f;
    #pragma unroll
    for (int kc = 0; kc < 5; ++kc) s += linpart[((long)kc * AP + a) * NH + col];
    v = (c < 2) ? (s + cls_b[c]) : (anchors[(long)a * 77 + c] + s + reg_b[c - 3]);
  }
  out_b[idx] = v;
}

extern "C" void kernel_launch(void* const* d_in, const int* in_sizes, int n_in,
                              void* d_out, int out_size, void* d_ws, size_t ws_size,
                              hipStream_t stream)
{
  (void)in_sizes; (void)n_in; (void)out_size; (void)ws_size;
  const float* x        = (const float*)d_in[0];
  const float* conv1_w  = (const float*)d_in[1];
  const float* conv1_b  = (const float*)d_in[2];
  const float* att_w    = (const float*)d_in[3];
  const float* att_b    = (const float*)d_in[4];
  const float* cls_w    = (const float*)d_in[5];
  const float* cls_b    = (const float*)d_in[6];
  const float* reg_w    = (const float*)d_in[7];
  const float* reg_b    = (const float*)d_in[8];
  const float* anchors  = (const float*)d_in[9];
  const int*   cut_xs   = (const int*)d_in[10];
  const int*   invalid  = (const int*)d_in[11];
  float* out = (float*)d_out;

  auto align256 = [](size_t v) { return (v + 255) & ~(size_t)255; };
  char* ws = (char*)d_ws;
  float* feats    = (float*)ws;  ws += align256((size_t)BB * TT * CAF * HH * WW * 4);  // 1.8 MB
  short* attwT    = (short*)ws;  ws += align256((size_t)AP * DD * 2);                  // 4.0 MB
  short* headwT   = (short*)ws;  ws += align256((size_t)NH * KH * 2);                  // 0.6 MB
  short* rois_b   = (short*)ws;  ws += align256((size_t)TT * AP * DD * 2);             // 15.9 MB
  short* curT_b   = (short*)ws;  ws += align256((size_t)DP * AP * 2);                  // 4.3 MB
  short* scores_b = (short*)ws;  ws += align256((size_t)AP * AP * 2);                  // 15.9 MB
  short* attft_b  = (short*)ws;  ws += align256((size_t)AP * DP * 2);                  // 4.3 MB
  float* linpart  = (float*)ws;  ws += align256((size_t)5 * AP * NH * 4);              // 4.5 MB
  // total ~51.3 MB

  conv_kernel<<<dim3(BB * TT, HH), 256, 0, stream>>>(x, conv1_w, conv1_b, feats);
  prep_attw_kernel<<<dim3(AP / 32, DD / 32), 256, 0, stream>>>(att_w, attwT);
  prep_headw_kernel<<<(NH * KH + 255) / 256, 256, 0, stream>>>(cls_w, reg_w, headwT);

  for (int b = 0; b < BB; ++b) {
    const float* feats_b = feats + (long)b * TT * CAF * HH * WW;

    gather_kernel<<<dim3(AP / 4, TT), 256, 0, stream>>>(feats_b, cut_xs, invalid, rois_b);
    transpose_cur_kernel<<<dim3(AP / 32, DP / 32), 256, 0, stream>>>(rois_b, curT_b);

    // scores = cur @ att_w^T(+att_b): A = rois_b t=3 [AP][704], Bt = attwT [AP][704]
    gemm_nt_kernel<1><<<dim3(AP / 128, AP / 128), 256, 0, stream>>>(
        rois_b + (long)3 * AP * DD, DD, attwT, DD, scores_b, AP, DD, att_b, NATT);

    softmax_shift_kernel<<<AREAL, 256, 0, stream>>>(scores_b);

    // att_feat = Mfull @ cur: A = scores_b [AP][AP], Bt = curT_b [DP][AP]
    gemm_nt_kernel<0><<<dim3(DP / 128, AP / 128), 256, 0, stream>>>(
        scores_b, AP, curT_b, AP, attft_b, DP, AP, nullptr, 0);

    gemm_heads_split<<<dim3(5, AP / 128), 256, 0, stream>>>(rois_b, attft_b, headwT, linpart);

    assemble_kernel<<<(int)(((long)AREAL * 77 + 255) / 256), 256, 0, stream>>>(
        linpart, anchors, cls_b, reg_b, out + (long)b * AREAL * 77);
  }
}